// Round 9
// baseline (233.613 us; speedup 1.0000x reference)
//
#include <hip/hip_runtime.h>
#include <math.h>

#define TT 1024
#define BB 4
#define HH 1024
#define NHH 32
#define CL 64
#define NCH (TT/CL)

typedef unsigned short u16;
typedef __attribute__((ext_vector_type(8))) short short8;
typedef __attribute__((ext_vector_type(8))) unsigned short u16x8;
typedef __attribute__((ext_vector_type(4))) float floatx4;

__device__ __forceinline__ float sigmoidf_(float x){ return 1.f/(1.f+expf(-x)); }
__device__ __forceinline__ u16 f2b(float f){
  union { float f; unsigned u; } x; x.f = f;
  unsigned r = x.u + 0x7FFFu + ((x.u >> 16) & 1u);
  return (u16)(r >> 16);
}
__device__ __forceinline__ float b2f(u16 v){
  union { unsigned u; float f; } x; x.u = ((unsigned)v) << 16;
  return x.f;
}

// ---------------- cast fp32 -> bf16 (x, [Wq|Wk|Wv|Wbeta|Wmix], Wout) + rope table ----------------
__global__ __launch_bounds__(256) void cast_all_k(
    const float* __restrict__ x, const float* __restrict__ Wq, const float* __restrict__ Wk,
    const float* __restrict__ Wv, const float* __restrict__ Wbeta, const float* __restrict__ Wmix,
    const float* __restrict__ Wout,
    u16* __restrict__ x_bf, u16* __restrict__ Wf, u16* __restrict__ Wout_bf,
    float* __restrict__ ct, float* __restrict__ st)
{
  int gid = blockIdx.x*256 + threadIdx.x;
  if (gid < 16384) {   // rope table: t=gid>>4, j=gid&15
    int t = gid >> 4, j = gid & 15;
    float invf = powf(10000.f, -(float)j/16.f);
    float ang = (float)t * invf;
    ct[gid] = cosf(ang);
    st[gid] = sinf(ang);
  }
  size_t e = (size_t)gid*4;   // 8519680 total elems
  const float* src; u16* dst; size_t so, dof;
  if      (e < 4194304) { src=x;     dst=x_bf;    so=e;          dof=so; }
  else if (e < 5242880) { src=Wq;    dst=Wf;      so=e-4194304;  dof=so; }
  else if (e < 6291456) { src=Wk;    dst=Wf;      so=e-5242880;  dof=so+1048576; }
  else if (e < 7340032) { src=Wv;    dst=Wf;      so=e-6291456;  dof=so+2097152; }
  else if (e < 7405568) { src=Wbeta; dst=Wf;      so=e-7340032;  dof=so+3145728; }
  else if (e < 7471104) { src=Wmix;  dst=Wf;      so=e-7405568;  dof=so+3211264; }
  else                  { src=Wout;  dst=Wout_bf; so=e-7471104;  dof=so; }
  float4 f = *reinterpret_cast<const float4*>(src + so);
  ushort4 u; u.x=f2b(f.x); u.y=f2b(f.y); u.z=f2b(f.z); u.w=f2b(f.w);
  *reinterpret_cast<ushort4*>(dst + dof) = u;
}

// ---------------- fused QKV+beta/mix GEMM, N=3200, rope/elu epilogue ----------------
// 2-D grid (25,32), col-fastest dispatch (measured best: 56us vs row-fastest 75us, 3x replicated).
// Lean epilogue keeps VGPR<=100 -> 5 blocks/CU. Do NOT cap registers (R6: spill disaster).
__global__ __launch_bounds__(256) void gemm_qkv_k(
    const u16* __restrict__ A, const u16* __restrict__ W,
    const float* __restrict__ ct, const float* __restrict__ st,
    u16* __restrict__ qkv, float* __restrict__ bmraw)
{
  __shared__ u16 As[128*64];
  __shared__ u16 Ws[128*64];
  const int tid = threadIdx.x;
  const int lane = tid & 63;
  const int wave = tid >> 6;
  const int wm = wave >> 1, wn = wave & 1;
  const int bx = blockIdx.x;
  const int row0 = blockIdx.y*128, col0 = bx*128;
  const int lr = lane & 15, lkg = lane >> 4;

  floatx4 acc[4][4];
  #pragma unroll
  for (int mt=0; mt<4; ++mt)
    #pragma unroll
    for (int nt=0; nt<4; ++nt)
      acc[mt][nt] = (floatx4){0.f,0.f,0.f,0.f};

  for (int k0 = 0; k0 < 1024; k0 += 64) {
    __syncthreads();
    #pragma unroll
    for (int it = 0; it < 4; ++it) {
      int li  = it*256 + tid;
      int row = li >> 3, ckp = li & 7;
      int ck  = ckp ^ (row & 7);
      const u16* ga = A + (size_t)(row0+row)*1024 + k0 + ck*8;
      const u16* gw = W + (size_t)(col0+row)*1024 + k0 + ck*8;
      __builtin_amdgcn_global_load_lds(
          (const __attribute__((address_space(1))) void*)ga,
          (__attribute__((address_space(3))) void*)(As + (size_t)(li & ~63)*8), 16, 0, 0);
      __builtin_amdgcn_global_load_lds(
          (const __attribute__((address_space(1))) void*)gw,
          (__attribute__((address_space(3))) void*)(Ws + (size_t)(li & ~63)*8), 16, 0, 0);
    }
    __syncthreads();
    #pragma unroll
    for (int kk = 0; kk < 64; kk += 32) {
      short8 af[4], wf[4];
      const int ckw = (kk >> 3) + lkg;
      #pragma unroll
      for (int t = 0; t < 4; ++t) {
        int rowA = wm*64 + t*16 + lr;
        int rowW = wn*64 + t*16 + lr;
        af[t] = *reinterpret_cast<const short8*>(As + rowA*64 + (ckw ^ (rowA & 7))*8);
        wf[t] = *reinterpret_cast<const short8*>(Ws + rowW*64 + (ckw ^ (rowW & 7))*8);
      }
      #pragma unroll
      for (int mt = 0; mt < 4; ++mt)
        #pragma unroll
        for (int nt = 0; nt < 4; ++nt)
          acc[mt][nt] = __builtin_amdgcn_mfma_f32_16x16x32_bf16(af[mt], wf[nt], acc[mt][nt], 0, 0, 0);
    }
  }
  if (bx < 16) {
    // q/k region: rope + elu+1
    #pragma unroll
    for (int mt = 0; mt < 4; ++mt) {
      #pragma unroll
      for (int r = 0; r < 4; ++r) {
        int row = row0 + wm*64 + mt*16 + lkg*4 + r;
        int t = row & (TT-1);
        float c_ = ct[t*16 + lr], s_ = st[t*16 + lr];
        #pragma unroll
        for (int nt = 0; nt < 4; nt += 2) {
          float u1 = acc[mt][nt][r], u2 = acc[mt][nt+1][r];
          float r1 = u1*c_ - u2*s_;
          float r2 = u1*s_ + u2*c_;
          r1 = r1 > 0.f ? r1+1.f : expf(r1);
          r2 = r2 > 0.f ? r2+1.f : expf(r2);
          int col = col0 + wn*64 + nt*16 + lr;
          qkv[(size_t)row*3072 + col]      = f2b(r1);
          qkv[(size_t)row*3072 + col + 16] = f2b(r2);
        }
      }
    }
  } else if (bx < 24) {
    // v region: passthrough bf16
    #pragma unroll
    for (int mt = 0; mt < 4; ++mt)
      #pragma unroll
      for (int r = 0; r < 4; ++r) {
        int row = row0 + wm*64 + mt*16 + lkg*4 + r;
        #pragma unroll
        for (int nt = 0; nt < 4; ++nt) {
          int col = col0 + wn*64 + nt*16 + lr;
          qkv[(size_t)row*3072 + col] = f2b(acc[mt][nt][r]);
        }
      }
  } else {
    // beta/mix raw fp32 -> bmraw[row][0..127]
    #pragma unroll
    for (int mt = 0; mt < 4; ++mt)
      #pragma unroll
      for (int r = 0; r < 4; ++r) {
        int row = row0 + wm*64 + mt*16 + lkg*4 + r;
        #pragma unroll
        for (int nt = 0; nt < 4; ++nt) {
          int col = col0 + wn*64 + nt*16 + lr - 3072;
          bmraw[(size_t)row*128 + col] = acc[mt][nt][r];
        }
      }
  }
}

// ---------------- out-projection: z = y @ Wout^T + bout + x (fp32, full K) ----------------
__global__ __launch_bounds__(256) void gemm_out_k(
    const u16* __restrict__ A, const u16* __restrict__ W,
    const float* __restrict__ xr, const float* __restrict__ bout,
    float* __restrict__ Z)
{
  __shared__ u16 As[128*64];
  __shared__ u16 Ws[64*64];
  const int tid = threadIdx.x;
  const int lane = tid & 63;
  const int wave = tid >> 6;
  const int row0 = blockIdx.y*128, col0 = blockIdx.x*64;
  const int lr = lane & 15, lkg = lane >> 4;
  floatx4 acc[2][4];
  #pragma unroll
  for (int mt=0; mt<2; ++mt)
    #pragma unroll
    for (int nt=0; nt<4; ++nt)
      acc[mt][nt] = (floatx4){0.f,0.f,0.f,0.f};
  for (int k0 = 0; k0 < 1024; k0 += 64) {
    __syncthreads();
    #pragma unroll
    for (int it = 0; it < 4; ++it) {
      int li  = it*256 + tid;
      int row = li >> 3, ckp = li & 7;
      int ck  = ckp ^ (row & 7);
      const u16* ga = A + (size_t)(row0+row)*1024 + k0 + ck*8;
      __builtin_amdgcn_global_load_lds(
          (const __attribute__((address_space(1))) void*)ga,
          (__attribute__((address_space(3))) void*)(As + (size_t)(li & ~63)*8), 16, 0, 0);
    }
    #pragma unroll
    for (int it = 0; it < 2; ++it) {
      int li  = it*256 + tid;
      int row = li >> 3, ckp = li & 7;
      int ck  = ckp ^ (row & 7);
      const u16* gw = W + (size_t)(col0+row)*1024 + k0 + ck*8;
      __builtin_amdgcn_global_load_lds(
          (const __attribute__((address_space(1))) void*)gw,
          (__attribute__((address_space(3))) void*)(Ws + (size_t)(li & ~63)*8), 16, 0, 0);
    }
    __syncthreads();
    #pragma unroll
    for (int kk = 0; kk < 64; kk += 32) {
      short8 af[2], wf[4];
      const int ckw = (kk >> 3) + lkg;
      #pragma unroll
      for (int t = 0; t < 2; ++t) {
        int rowA = wave*32 + t*16 + lr;
        af[t] = *reinterpret_cast<const short8*>(As + rowA*64 + (ckw ^ (rowA & 7))*8);
      }
      #pragma unroll
      for (int t = 0; t < 4; ++t) {
        int rowW = t*16 + lr;
        wf[t] = *reinterpret_cast<const short8*>(Ws + rowW*64 + (ckw ^ (rowW & 7))*8);
      }
      #pragma unroll
      for (int mt = 0; mt < 2; ++mt)
        #pragma unroll
        for (int nt = 0; nt < 4; ++nt)
          acc[mt][nt] = __builtin_amdgcn_mfma_f32_16x16x32_bf16(af[mt], wf[nt], acc[mt][nt], 0, 0, 0);
    }
  }
  #pragma unroll
  for (int mt = 0; mt < 2; ++mt)
    #pragma unroll
    for (int r = 0; r < 4; ++r) {
      int row = row0 + wave*32 + mt*16 + lkg*4 + r;
      #pragma unroll
      for (int nt = 0; nt < 4; ++nt) {
        int col = col0 + nt*16 + lr;
        Z[(size_t)row*HH + col] = acc[mt][nt][r] + bout[col] + xr[(size_t)row*HH + col];
      }
    }
}

// ---------------- fused scan: delta + prefix + apply in one kernel ----------------
// grid (chalf=2, h=32, b=4) = 256 blocks (1/CU). Each block: one (b,h), one 16-col V-half,
// both m. S (2x32x16 fp32) and K0 live in LDS across the 16 sequential chunks.
// Register-prefetch of chunk ch+1 issued before chunk ch's compute.
__global__ __launch_bounds__(256) void scan_fused_k(
    const u16* __restrict__ qkv, const float* __restrict__ bmraw,
    const float* __restrict__ bbeta, const float* __restrict__ bmix,
    u16* __restrict__ yb)
{
  __shared__ __align__(16) u16 Qs[64][40], Ks[64][40];
  __shared__ __align__(16) u16 VT[16][72];
  __shared__ __align__(16) u16 K2T[2][32][72];
  __shared__ __align__(16) u16 At[2][64][72];
  __shared__ __align__(16) u16 S0T[2][2][16][40];   // [m][hi/lo][c][d]
  __shared__ float Ss[2][32][17];                    // fp32 state [m][d][c]
  __shared__ float K0s[2][32];
  __shared__ float bets[2][64], pbv[2][64], ipb[2][64], wjs[2][64], mixs[2][64], coef[2][64];
  __shared__ float pLs[2];

  const int chalf = blockIdx.x, h = blockIdx.y, b = blockIdx.z;
  const int tid = threadIdx.x;
  const int lane = tid & 63, wv = tid >> 6;
  const int lr = lane & 15, kg = lane >> 4;
  const int jrow = tid >> 2, oct = tid & 3;

  for (int u = tid; u < 2*32*17; u += 256) ((float*)Ss)[u] = 0.f;
  if (tid < 64) K0s[tid>>5][tid&31] = 0.f;

  const float bb  = (tid < 128) ? bbeta[h*2 + (tid&1)] : 0.f;
  const float bm0 = bmix[h*2], bm1 = bmix[h*2+1];

  // prefetch chunk 0
  u16x8 q8, k8; ushort4 v4; float bmv = 0.f, mr0 = 0.f, mr1 = 0.f;
  {
    size_t rb = (size_t)(b*TT + jrow)*3072 + h*32;
    q8 = *reinterpret_cast<const u16x8*>(qkv + rb + oct*8);
    k8 = *reinterpret_cast<const u16x8*>(qkv + rb + 1024 + oct*8);
    v4 = *reinterpret_cast<const ushort4*>(qkv + rb + 2048 + chalf*16 + oct*4);
    if (tid < 128) bmv = bmraw[(size_t)(b*TT + (tid>>1))*128 + h*2 + (tid&1)];
    else if (tid < 192) {
      int i = tid - 128;
      size_t mb = (size_t)(b*TT + i)*128 + 64 + h*2;
      mr0 = bmraw[mb]; mr1 = bmraw[mb+1];
    }
  }

  for (int ch = 0; ch < NCH; ++ch) {
    const int t0 = ch*CL;
    __syncthreads();                                   // B0: prev chunk done, LDS free
    // ---- stage current chunk into LDS ----
    *reinterpret_cast<u16x8*>(&Qs[jrow][oct*8]) = q8;
    *reinterpret_cast<u16x8*>(&Ks[jrow][oct*8]) = k8;
    u16x8 k8c = k8;
    {
      const u16* vp = reinterpret_cast<const u16*>(&v4);
      #pragma unroll
      for (int u2 = 0; u2 < 4; ++u2) VT[oct*4+u2][jrow] = vp[u2];
    }
    float mr0c = mr0, mr1c = mr1;
    if (tid < 128) bets[tid&1][tid>>1] = fminf(fmaxf(sigmoidf_(bmv + bb), 0.85f), 0.9995f);
    // ---- prefetch next chunk ----
    if (ch < NCH-1) {
      int t0n = t0 + CL;
      size_t rb = (size_t)(b*TT + t0n + jrow)*3072 + h*32;
      q8 = *reinterpret_cast<const u16x8*>(qkv + rb + oct*8);
      k8 = *reinterpret_cast<const u16x8*>(qkv + rb + 1024 + oct*8);
      v4 = *reinterpret_cast<const ushort4*>(qkv + rb + 2048 + chalf*16 + oct*4);
      if (tid < 128) bmv = bmraw[(size_t)(b*TT + t0n + (tid>>1))*128 + h*2 + (tid&1)];
      else if (tid < 192) {
        int i = tid - 128;
        size_t mb = (size_t)(b*TT + t0n + i)*128 + 64 + h*2;
        mr0 = bmraw[mb]; mr1 = bmraw[mb+1];
      }
    }
    __syncthreads();                                   // B1: staged
    // ---- beta cumprod (waves 0,1) ; mixs (tid 128..191) ; A0 raw (all) ; S->S0T ----
    if (tid < 128) {
      float p = bets[wv][lane];
      #pragma unroll
      for (int off = 1; off < 64; off <<= 1) {
        float o = __shfl_up(p, off);
        if (lane >= off) p *= o;
      }
      float pl = __shfl(p, 63);
      pbv[wv][lane] = p;
      ipb[wv][lane] = 1.f/p;
      wjs[wv][lane] = pl/p;
      if (lane == 63) pLs[wv] = p;
    } else if (tid < 192) {
      int i = tid - 128;
      float a0v = mr0c + bm0, a1v = mr1c + bm1;
      float mx = fmaxf(a0v, a1v);
      float e0 = expf(a0v-mx), e1 = expf(a1v-mx);
      float inv = 1.f/(e0+e1);
      mixs[0][i] = e0*inv; mixs[1][i] = e1*inv;
    }
    floatx4 a0r[4];
    {
      short8 aq = *reinterpret_cast<const short8*>(&Qs[wv*16 + lr][kg*8]);
      #pragma unroll
      for (int nt = 0; nt < 4; ++nt) {
        short8 bk = *reinterpret_cast<const short8*>(&Ks[nt*16 + lr][kg*8]);
        a0r[nt] = (floatx4){0.f,0.f,0.f,0.f};
        a0r[nt] = __builtin_amdgcn_mfma_f32_16x16x32_bf16(aq, bk, a0r[nt], 0, 0, 0);
      }
    }
    #pragma unroll
    for (int i2 = 0; i2 < 4; ++i2) {
      int e = tid*4 + i2;
      int m = e >> 9, rem = e & 511, c = rem >> 5, d = rem & 31;
      float val = Ss[m][d][c];
      u16 hv = f2b(val);
      S0T[m][0][c][d] = hv;
      S0T[m][1][c][d] = f2b(val - b2f(hv));
    }
    __syncthreads();                                   // B2: wjs/ipb/S0T ready
    // ---- write At (masked, ipb-scaled) and K2T (wj-scaled) ----
    #pragma unroll
    for (int nt = 0; nt < 4; ++nt) {
      int jg = nt*16 + lr;
      float ip0 = ipb[0][jg], ip1 = ipb[1][jg];
      #pragma unroll
      for (int r = 0; r < 4; ++r) {
        int ig = wv*16 + kg*4 + r;
        float val = a0r[nt][r];
        bool ok = (jg <= ig);
        At[0][ig][jg] = f2b(ok ? val*ip0 : 0.f);
        At[1][ig][jg] = f2b(ok ? val*ip1 : 0.f);
      }
    }
    {
      float w0 = wjs[0][jrow], w1 = wjs[1][jrow];
      #pragma unroll
      for (int dd = 0; dd < 8; ++dd) {
        float kv = b2f(k8c[dd]);
        K2T[0][oct*8+dd][jrow] = f2b(kv*w0);
        K2T[1][oct*8+dd][jrow] = f2b(kv*w1);
      }
    }
    __syncthreads();                                   // B3: At, K2T ready
    // ---- waves 0,1: den->coef ; waves 2,3: dS MFMA + S update ----
    if (tid < 128) {
      int m = tid & 1, i = tid >> 1;
      float qK0 = 0.f;
      #pragma unroll
      for (int g = 0; g < 4; ++g) {
        u16x8 qq = *reinterpret_cast<const u16x8*>(&Qs[i][g*8]);
        #pragma unroll
        for (int dd = 0; dd < 8; ++dd) qK0 = fmaf(b2f(qq[dd]), K0s[m][g*8+dd], qK0);
      }
      float As_ = 0.f;
      #pragma unroll
      for (int g = 0; g < 8; ++g) {
        u16x8 aa = *reinterpret_cast<const u16x8*>(&At[m][i][g*8]);
        #pragma unroll
        for (int dd = 0; dd < 8; ++dd) As_ += b2f(aa[dd]);
      }
      float den = pbv[m][i]*(qK0 + As_) + 1e-6f;
      coef[m][i] = mixs[m][i]*pbv[m][i]/den;
    } else {
      int m = wv - 2;
      float pl = pLs[m];
      #pragma unroll
      for (int dt = 0; dt < 2; ++dt) {
        floatx4 acc = (floatx4){0.f,0.f,0.f,0.f};
        #pragma unroll
        for (int ks = 0; ks < 2; ++ks) {
          short8 af = *reinterpret_cast<const short8*>(&K2T[m][dt*16 + lr][ks*32 + kg*8]);
          short8 bv = *reinterpret_cast<const short8*>(&VT[lr][ks*32 + kg*8]);
          acc = __builtin_amdgcn_mfma_f32_16x16x32_bf16(af, bv, acc, 0, 0, 0);
        }
        #pragma unroll
        for (int r = 0; r < 4; ++r) {
          int d = dt*16 + kg*4 + r;
          Ss[m][d][lr] = fmaf(pl, Ss[m][d][lr], acc[r]);
        }
      }
    }
    __syncthreads();                                   // B4: coef ready
    // ---- y = sum_m coef_m * (Q S0_m + At_m V) ; K0 update ----
    {
      floatx4 accY[2];
      short8 aq = *reinterpret_cast<const short8*>(&Qs[wv*16 + lr][kg*8]);
      #pragma unroll
      for (int m = 0; m < 2; ++m) {
        accY[m] = (floatx4){0.f,0.f,0.f,0.f};
        short8 bhi = *reinterpret_cast<const short8*>(&S0T[m][0][lr][kg*8]);
        short8 blo = *reinterpret_cast<const short8*>(&S0T[m][1][lr][kg*8]);
        accY[m] = __builtin_amdgcn_mfma_f32_16x16x32_bf16(aq, bhi, accY[m], 0, 0, 0);
        accY[m] = __builtin_amdgcn_mfma_f32_16x16x32_bf16(aq, blo, accY[m], 0, 0, 0);
        #pragma unroll
        for (int ks = 0; ks < 2; ++ks) {
          short8 af = *reinterpret_cast<const short8*>(&At[m][wv*16 + lr][ks*32 + kg*8]);
          short8 bv = *reinterpret_cast<const short8*>(&VT[lr][ks*32 + kg*8]);
          accY[m] = __builtin_amdgcn_mfma_f32_16x16x32_bf16(af, bv, accY[m], 0, 0, 0);
        }
      }
      #pragma unroll
      for (int r = 0; r < 4; ++r) {
        int i = wv*16 + kg*4 + r;
        float c0 = coef[0][i], c1 = coef[1][i];
        yb[(size_t)(b*TT + t0 + i)*HH + h*32 + chalf*16 + lr]
            = f2b(c0*accY[0][r] + c1*accY[1][r]);
      }
    }
    if (tid < 64) {
      int m = tid >> 5, d = tid & 31;
      float s = 0.f;
      #pragma unroll
      for (int g = 0; g < 8; ++g) {
        u16x8 kk = *reinterpret_cast<const u16x8*>(&K2T[m][d][g*8]);
        #pragma unroll
        for (int dd = 0; dd < 8; ++dd) s += b2f(kk[dd]);
      }
      K0s[m][d] = fmaf(pLs[m], K0s[m][d], s);
    }
  }
}

// ---------------- LayerNorm over rows of z ----------------
__global__ __launch_bounds__(256) void ln_k(
    const float* __restrict__ z, const float* __restrict__ g,
    const float* __restrict__ bta, float* __restrict__ out)
{
  const int row = blockIdx.x;
  const int tid = threadIdx.x;
  size_t o = (size_t)row*HH/4 + tid;
  float4 zv = reinterpret_cast<const float4*>(z)[o];
  float sum = zv.x+zv.y+zv.z+zv.w;
  float sq  = zv.x*zv.x + zv.y*zv.y + zv.z*zv.z + zv.w*zv.w;
  #pragma unroll
  for (int off=1; off<64; off<<=1){ sum += __shfl_xor(sum, off); sq += __shfl_xor(sq, off); }
  __shared__ float s1[4], s2[4];
  int w = tid>>6;
  if ((tid&63)==0){ s1[w]=sum; s2[w]=sq; }
  __syncthreads();
  sum = s1[0]+s1[1]+s1[2]+s1[3];
  sq  = s2[0]+s2[1]+s2[2]+s2[3];
  float mu  = sum * (1.f/1024.f);
  float var = sq * (1.f/1024.f) - mu*mu;
  float rstd = rsqrtf(var + 1e-5f);
  float4 gv = reinterpret_cast<const float4*>(g)[tid];
  float4 bv = reinterpret_cast<const float4*>(bta)[tid];
  float4 ov;
  ov.x = (zv.x-mu)*rstd*gv.x + bv.x;
  ov.y = (zv.y-mu)*rstd*gv.y + bv.y;
  ov.z = (zv.z-mu)*rstd*gv.z + bv.z;
  ov.w = (zv.w-mu)*rstd*gv.w + bv.w;
  reinterpret_cast<float4*>(out)[o] = ov;
}

extern "C" void kernel_launch(void* const* d_in, const int* in_sizes, int n_in,
                              void* d_out, int out_size, void* d_ws, size_t ws_size,
                              hipStream_t stream)
{
  const float* x     = (const float*)d_in[0];
  const float* Wq    = (const float*)d_in[1];
  const float* Wk    = (const float*)d_in[2];
  const float* Wv    = (const float*)d_in[3];
  const float* Wbeta = (const float*)d_in[4];
  const float* bbeta = (const float*)d_in[5];
  const float* Wmix  = (const float*)d_in[6];
  const float* bmix  = (const float*)d_in[7];
  const float* Wout  = (const float*)d_in[8];
  const float* bout  = (const float*)d_in[9];
  const float* ln_g  = (const float*)d_in[10];
  const float* ln_b  = (const float*)d_in[11];
  float* out = (float*)d_out;

  float* ws = (float*)d_ws;
  float* ct      = ws;                       // 16384
  float* st      = ws + 16384;               // 16384
  u16*   x_bf    = (u16*)(ws + 32768);       // 4194304 u16 (reused as y_bf)
  u16*   Wf      = (u16*)(ws + 2129920);     // 3276800 u16
  u16*   Wout_bf = (u16*)(ws + 3768320);     // 1048576 u16
  u16*   qkv     = (u16*)(ws + 4292608);     // 12582912 u16
  float* bmraw   = ws + 10584064;            // 524288
  float* z       = ws + 11108352;            // 4194304
  u16*   y_bf    = x_bf;

  cast_all_k<<<8320, 256, 0, stream>>>(x, Wq, Wk, Wv, Wbeta, Wmix, Wout,
                                       x_bf, Wf, Wout_bf, ct, st);
  gemm_qkv_k<<<dim3(25, 32), 256, 0, stream>>>(x_bf, Wf, ct, st, qkv, bmraw);
  scan_fused_k<<<dim3(2, 32, 4), 256, 0, stream>>>(qkv, bmraw, bbeta, bmix, y_bf);
  gemm_out_k<<<dim3(16, 32), 256, 0, stream>>>(y_bf, Wout_bf, x, bout, z);
  ln_k<<<4096, 256, 0, stream>>>(z, ln_g, ln_b, out);
}